// Round 11
// baseline (208.649 us; speedup 1.0000x reference)
//
#include <hip/hip_runtime.h>
#include <hip/hip_bf16.h>

#define S_LEN 2048
#define HIDV  3072
#define NHQ   24
#define NKVH  8
#define HDIM  128

typedef __bf16 bf16x8 __attribute__((ext_vector_type(8)));
typedef float  f32x4  __attribute__((ext_vector_type(4)));
typedef int    i32x4  __attribute__((ext_vector_type(4)));

__device__ __forceinline__ void gload_lds16(const void* g, void* l) {
    __builtin_amdgcn_global_load_lds((__attribute__((address_space(1))) void*)g,
                                     (__attribute__((address_space(3))) void*)l, 16, 0, 0);
}

// ---------------- fused cast f32 -> bf16 over 5 regions, 4 elems/thread ----------------
__global__ void cast_all(const float* __restrict__ hs, const float* __restrict__ wq,
                         const float* __restrict__ wk, const float* __restrict__ wv,
                         const float* __restrict__ wo,
                         __hip_bfloat16* __restrict__ hsb, __hip_bfloat16* __restrict__ wf,
                         __hip_bfloat16* __restrict__ wob) {
    int c = blockIdx.x * blockDim.x + threadIdx.x;   // chunk of 4 f32
    const float* src; __hip_bfloat16* dst; int off;
    if (c < 1572864)      { src = hs; dst = hsb;            off = c; }
    else if (c < 3932160) { src = wq; dst = wf;             off = c - 1572864; }
    else if (c < 4718592) { src = wk; dst = wf + 9437184;   off = c - 3932160; }
    else if (c < 5505024) { src = wv; dst = wf + 12582912;  off = c - 4718592; }
    else                  { src = wo; dst = wob;            off = c - 5505024; }
    float4 v = *(const float4*)(src + off * 4);
    union { __hip_bfloat16 h[4]; ushort4 u; } pk;
    pk.h[0] = __float2bfloat16(v.x);
    pk.h[1] = __float2bfloat16(v.y);
    pk.h[2] = __float2bfloat16(v.z);
    pk.h[3] = __float2bfloat16(v.w);
    *(ushort4*)(dst + off * 4) = pk.u;
}

// ============ 2-phase double-buffered GEMM, BM=128, BN=NF*32, BK=64, swizzled LDS ============
// (1) per-thread global source offsets hoisted out of the K-loop;
// (2) K-loop unrolled by 2 so the LDS buffer index is a compile-time constant.
template<int NF, int MODE>
__global__ __launch_bounds__(256) void gemm_tile(const __hip_bfloat16* __restrict__ A,
                                                 const __hip_bfloat16* __restrict__ B,
                                                 void* __restrict__ C0, void* __restrict__ C1,
                                                 void* __restrict__ C2)
{
    extern __shared__ __align__(16) char smem[];
    // As buf b: [b*16384, +16384)  (128 rows x 128 B, xor-swizzled)
    // Bs buf b: [32768 + b*NF*4096, +NF*4096)  (NF*32 rows x 128 B, xor-swizzled)
    const int tid = threadIdx.x;
    const int w    = tid >> 6;
    const int lane = tid & 63;
    const int lr = lane & 15, lg = lane >> 4;
    const int wr = w >> 1, wc = w & 1;

    const int wg = ((int)blockIdx.x & 7) * 64 + ((int)blockIdx.x >> 3);
    const int bn = wg >> 4, bm = wg & 15;

    f32x4 zf = {0.f, 0.f, 0.f, 0.f};
    f32x4 acc[4][NF];
#pragma unroll
    for (int i = 0; i < 4; ++i)
#pragma unroll
        for (int j = 0; j < NF; ++j) acc[i][j] = zf;

    const char* Ab = (const char*)A + (size_t)(bm * 128) * 6144;
    const char* Bb = (const char*)B + (size_t)(bn * NF * 32) * 6144;
    const int NT = 48;  // 3072 / 64

    // hoisted per-thread source offsets (swizzled), invariant across K-steps
    int gaof[4], gbof[NF];
#pragma unroll
    for (int u_ = 0; u_ < 4; ++u_) {
        int u = tid + 256 * u_;
        int r_ = u >> 3, o_ = (u & 7) * 16;
        gaof[u_] = r_ * 6144 + (o_ ^ ((r_ & 7) << 4));
    }
#pragma unroll
    for (int u_ = 0; u_ < NF; ++u_) {
        int u = tid + 256 * u_;
        int r_ = u >> 3, o_ = (u & 7) * 16;
        gbof[u_] = r_ * 6144 + (o_ ^ ((r_ & 7) << 4));
    }

#define GT_STAGE(BUF, t) do {                                                       \
        const char* Abk_ = Ab + ((t) << 7);                                         \
        const char* Bbk_ = Bb + ((t) << 7);                                         \
        _Pragma("unroll")                                                           \
        for (int u_ = 0; u_ < 4; ++u_)                                              \
            gload_lds16(Abk_ + gaof[u_], smem + (BUF) * 16384 + tid * 16 + u_ * 4096); \
        _Pragma("unroll")                                                           \
        for (int u_ = 0; u_ < NF; ++u_)                                             \
            gload_lds16(Bbk_ + gbof[u_], smem + 32768 + (BUF) * (NF * 4096) + tid * 16 + u_ * 4096); \
    } while (0)

#define GT_COMPUTE(BUF) do {                                                        \
        bf16x8 af[4][2], bfr[NF][2];                                                \
        _Pragma("unroll")                                                           \
        for (int i = 0; i < 4; ++i) {                                               \
            int row = wr * 64 + i * 16 + lr;                                        \
            _Pragma("unroll")                                                       \
            for (int kk = 0; kk < 2; ++kk) {                                        \
                int cb = (kk * 64 + lg * 16) ^ ((row & 7) << 4);                    \
                af[i][kk] = *(const bf16x8*)(smem + (BUF) * 16384 + row * 128 + cb); \
            }                                                                       \
        }                                                                           \
        _Pragma("unroll")                                                           \
        for (int j = 0; j < NF; ++j) {                                              \
            int row = (wc * NF + j) * 16 + lr;                                      \
            _Pragma("unroll")                                                       \
            for (int kk = 0; kk < 2; ++kk) {                                        \
                int cb = (kk * 64 + lg * 16) ^ ((row & 7) << 4);                    \
                bfr[j][kk] = *(const bf16x8*)(smem + 32768 + (BUF) * (NF * 4096) + row * 128 + cb); \
            }                                                                       \
        }                                                                           \
        _Pragma("unroll")                                                           \
        for (int mi = 0; mi < 4; ++mi)                                              \
            _Pragma("unroll")                                                       \
            for (int ni = 0; ni < NF; ++ni)                                         \
                _Pragma("unroll")                                                   \
                for (int kk = 0; kk < 2; ++kk)                                      \
                    acc[mi][ni] = __builtin_amdgcn_mfma_f32_16x16x32_bf16(af[mi][kk], bfr[ni][kk], acc[mi][ni], 0, 0, 0); \
    } while (0)

    GT_STAGE(0, 0);
    __syncthreads();

    for (int t = 0; t < NT; t += 2) {
        GT_STAGE(1, t + 1);          // odd tile -> buf1
        GT_COMPUTE(0);               // even tile from buf0
        __syncthreads();
        if (t + 2 < NT) GT_STAGE(0, t + 2);
        GT_COMPUTE(1);
        __syncthreads();
    }
#undef GT_STAGE
#undef GT_COMPUTE

#pragma unroll
    for (int mi = 0; mi < 4; ++mi)
#pragma unroll
        for (int ni = 0; ni < NF; ++ni) {
            int row0 = bm * 128 + wr * 64 + mi * 16 + lg * 4;
            int col  = bn * NF * 32 + wc * NF * 16 + ni * 16 + lr;
            f32x4 v = acc[mi][ni];
            if (MODE == 0) {
#pragma unroll
                for (int j = 0; j < 4; ++j)
                    ((float*)C0)[(size_t)(row0 + j) * 3072 + col] = v[j];
            } else {
                if (col < 3072) {
#pragma unroll
                    for (int j = 0; j < 4; ++j)
                        ((__hip_bfloat16*)C0)[(size_t)(row0 + j) * 3072 + col] = __float2bfloat16(v[j]);
                } else if (col < 4096) {
#pragma unroll
                    for (int j = 0; j < 4; ++j)
                        ((__hip_bfloat16*)C1)[(size_t)(row0 + j) * 1024 + (col - 3072)] = __float2bfloat16(v[j]);
                } else {
                    union { __hip_bfloat16 h[4]; ushort4 u; } pk;
#pragma unroll
                    for (int j = 0; j < 4; ++j) pk.h[j] = __float2bfloat16(v[j]);
                    *(ushort4*)((__hip_bfloat16*)C2 + (size_t)(col - 4096) * 2048 + row0) = pk.u;
                }
            }
        }
}

// ---------------- fused RMSNorm + RoPE (q then k): one wave per row of 128 ----------------
__global__ void norm_rope_fused(const __hip_bfloat16* __restrict__ qpre,
                                const __hip_bfloat16* __restrict__ kpre,
                                __hip_bfloat16* __restrict__ qb, __hip_bfloat16* __restrict__ kb,
                                const float* __restrict__ qnw, const float* __restrict__ knw,
                                const float* __restrict__ cosp, const float* __restrict__ sinp)
{
    int gw = blockIdx.x * 4 + (threadIdx.x >> 6);
    int lane = threadIdx.x & 63;
    const __hip_bfloat16* row;
    const float* nw;
    __hip_bfloat16* outp;
    int s;
    if (gw < 49152) {  // Q: s = gw/24, h = gw%24
        s = gw / 24; int h = gw - s * 24;
        row  = qpre + (size_t)s * 3072 + h * HDIM;
        outp = qb   + (size_t)s * 3072 + h * HDIM;
        nw = qnw;
    } else {           // K: s = g/8, h = g%8; out kb[h][s][d]
        int g = gw - 49152;
        s = g >> 3; int h = g & 7;
        row  = kpre + (size_t)s * 1024 + h * HDIM;
        outp = kb + (size_t)h * 262144 + (size_t)s * 128;
        nw = knw;
    }
    float x1 = __bfloat162float(row[lane]), x2 = __bfloat162float(row[lane + 64]);
    float ss = x1 * x1 + x2 * x2;
#pragma unroll
    for (int xm = 1; xm < 64; xm <<= 1) ss += __shfl_xor(ss, xm, 64);
    float rs = rsqrtf(ss * (1.f / 128.f) + 1e-6f);
    float n1 = x1 * rs * (1.f + nw[lane]);
    float n2 = x2 * rs * (1.f + nw[lane + 64]);
    float c1 = cosp[s * HDIM + lane], c2 = cosp[s * HDIM + lane + 64];
    float s1 = sinp[s * HDIM + lane], s2 = sinp[s * HDIM + lane + 64];
    outp[lane]      = __float2bfloat16(n1 * c1 - n2 * s1);
    outp[lane + 64] = __float2bfloat16(n2 * c2 + n1 * s2);
}

// ---------------- Flash attention: GQA-fused, double-buffered K/V, XCD-pinned ----------------
// Grid 256 linear: kh = bid & 7 (round-robin dispatch -> all 32 blocks of a kv-head land
// on ONE XCD, whose L2 then holds that head's 1 MB K/V -> staging is L2-latency, and
// FETCH drops ~75->~25 MB). pb = bid >> 3. 384 thr / 6 waves = 3 q-heads x 2 strips;
// q half-tiles {pb, 63-pb} -> 33 balanced iters; exactly 1 block/CU.
__global__ __launch_bounds__(384) void attn_kernel(
    const __hip_bfloat16* __restrict__ Q,
    const __hip_bfloat16* __restrict__ Kc,
    const __hip_bfloat16* __restrict__ Vt,
    __hip_bfloat16* __restrict__ O)
{
    extern __shared__ __align__(16) char smem[];
    const int bid = blockIdx.x;
    const int kh = bid & 7;      // XCD-pinned kv-head
    const int pb = bid >> 3;     // 0..31
    const int tid = threadIdx.x;
    const int w = tid >> 6;      // 0..5
    const int lane = tid & 63;
    const int lr = lane & 15, lg = lane >> 4;
    const int h = kh * 3 + (w >> 1);
    const int strip = w & 1;

    const char* kg = (const char*)(Kc + (size_t)kh * S_LEN * HDIM);
    const char* vg = (const char*)(Vt + (size_t)kh * HDIM * S_LEN);
    __hip_bfloat16* pw = (__hip_bfloat16*)(smem + 65536 + w * 2304);

    // hoisted per-thread staging offsets (swizzled), invariant across kv-tiles
    int ksrc[4], vsrc[4];
#pragma unroll
    for (int i_ = 0; i_ < 4; ++i_) {
        int base_ = (tid + 256 * i_) * 16;
        int kr_ = base_ >> 8, kc_ = base_ & 255;
        ksrc[i_] = kr_ * 256 + (kc_ ^ ((kr_ & 7) << 4));
        int vr_ = base_ >> 7, vc_ = base_ & 127;
        vsrc[i_] = vr_ * 4096 + (vc_ ^ ((vr_ & 7) << 4));
    }

#define ATT_STAGE(b, j0s) do {                                                      \
        if (tid < 256) {                                                            \
            const char* kgs_ = kg + (size_t)(j0s) * 256;                            \
            const char* vgs_ = vg + (size_t)(j0s) * 2;                              \
            _Pragma("unroll")                                                       \
            for (int i_ = 0; i_ < 4; ++i_) {                                        \
                gload_lds16(kgs_ + ksrc[i_], smem + (b) * 16384 + tid * 16 + i_ * 4096); \
                gload_lds16(vgs_ + vsrc[i_], smem + 32768 + (b) * 16384 + tid * 16 + i_ * 4096); \
            } } } while (0)

    for (int half = 0; half < 2; ++half) {
        const int hb = half ? (63 - pb) : pb;
        const int q0 = hb * 32;
        const int qrow = q0 + strip * 16;
        const int jtmax = (q0 + 31) >> 6;

        bf16x8 aq[4];
        {
            const __hip_bfloat16* qp = Q + (size_t)(qrow + lr) * HIDV + h * HDIM + lg * 8;
#pragma unroll
            for (int ks = 0; ks < 4; ++ks) aq[ks] = *(const bf16x8*)(qp + ks * 32);
        }

        f32x4 zf = {0.f, 0.f, 0.f, 0.f};
        f32x4 oacc[8];
#pragma unroll
        for (int i = 0; i < 8; ++i) oacc[i] = zf;
        float lacc[4] = {0.f, 0.f, 0.f, 0.f};

        ATT_STAGE(0, 0);
        __syncthreads();

        int buf = 0;
        for (int jt = 0; jt <= jtmax; ++jt) {
            if (jt < jtmax) ATT_STAGE(buf ^ 1, (jt + 1) * 64);

            const int j0 = jt * 64;
            const char* Kb = smem + buf * 16384;
            const char* Vb = smem + 32768 + buf * 16384;

            f32x4 sf[4];
#pragma unroll
            for (int nf = 0; nf < 4; ++nf) {
                sf[nf] = zf;
                int row = nf * 16 + lr;
#pragma unroll
                for (int ks = 0; ks < 4; ++ks) {
                    int boff = (row * 256 + ks * 64 + lg * 16) ^ ((row & 7) << 4);
                    bf16x8 bk = *(const bf16x8*)(Kb + boff);
                    sf[nf] = __builtin_amdgcn_mfma_f32_16x16x32_bf16(aq[ks], bk, sf[nf], 0, 0, 0);
                }
            }

            const bool diag = (jt == jtmax);
#pragma unroll
            for (int nf = 0; nf < 4; ++nf) {
                int jpos = j0 + nf * 16 + lr;
#pragma unroll
                for (int r = 0; r < 4; ++r) {
                    float sv = sf[nf][r];
                    float x2   = sv * sv * 3.125e-06f;               // x^2, x = sv*1.7677e-3
                    float poly = fmaf(x2, fmaf(x2, 0.13333333f, -0.33333333f), 1.0f);
                    float t    = sv * 0.08838834764831845f * poly;   // 50*tanh(x)
                    float p    = __expf(t - 30.f);                   // fixed-max softmax
                    if (diag && jpos > (qrow + lg * 4 + r)) p = 0.f;
                    lacc[r] += p;
                    pw[(lg * 4 + r) * 72 + nf * 16 + lr] = __float2bfloat16(p);
                }
            }

#pragma unroll
            for (int ks2 = 0; ks2 < 2; ++ks2) {
                bf16x8 ap = *(const bf16x8*)((const char*)pw + lr * 144 + ks2 * 64 + lg * 16);
#pragma unroll
                for (int df = 0; df < 8; ++df) {
                    int row = df * 16 + lr;
                    int boff = (row * 128 + ks2 * 64 + lg * 16) ^ ((row & 7) << 4);
                    bf16x8 bv = *(const bf16x8*)(Vb + boff);
                    oacc[df] = __builtin_amdgcn_mfma_f32_16x16x32_bf16(ap, bv, oacc[df], 0, 0, 0);
                }
            }
            __syncthreads();
            buf ^= 1;
        }

#pragma unroll
        for (int r = 0; r < 4; ++r) {
            float t = lacc[r];
#pragma unroll
            for (int xm = 1; xm < 16; xm <<= 1) t += __shfl_xor(t, xm, 64);
            float inv = __builtin_amdgcn_rcpf(t);
            size_t rowoff = (size_t)(qrow + lg * 4 + r) * HIDV + h * HDIM;
#pragma unroll
            for (int df = 0; df < 8; ++df)
                O[rowoff + df * 16 + lr] = __float2bfloat16(oacc[df][r] * inv);
        }
    }
#undef ATT_STAGE
}

extern "C" void kernel_launch(void* const* d_in, const int* in_sizes, int n_in,
                              void* d_out, int out_size, void* d_ws, size_t ws_size,
                              hipStream_t stream) {
    const float* hs   = (const float*)d_in[0];
    const float* cosp = (const float*)d_in[1];
    const float* sinp = (const float*)d_in[2];
    // d_in[3] attention_mask — exactly causal, applied analytically in attn_kernel
    const float* wq  = (const float*)d_in[4];
    const float* wk  = (const float*)d_in[5];
    const float* wv  = (const float*)d_in[6];
    const float* wo  = (const float*)d_in[7];
    const float* qnw = (const float*)d_in[8];
    const float* knw = (const float*)d_in[9];
    float* out = (float*)d_out;

    char* ws = (char*)d_ws;
    __hip_bfloat16* hsb  = (__hip_bfloat16*)(ws + 0);          // 2048x3072 bf16
    __hip_bfloat16* wf   = (__hip_bfloat16*)(ws + 12582912);   // 5120x3072 bf16 fused QKV weight
    __hip_bfloat16* wob  = (__hip_bfloat16*)(ws + 44040192);   // 3072x3072 bf16
    __hip_bfloat16* qpre = (__hip_bfloat16*)(ws + 62914560);   // 2048x3072 bf16 (pre-norm Q)
    __hip_bfloat16* kpre = (__hip_bfloat16*)(ws + 75497472);   // 2048x1024 bf16 (pre-norm K)
    __hip_bfloat16* qb   = (__hip_bfloat16*)(ws + 79691776);   // 2048x3072 bf16
    __hip_bfloat16* kb   = (__hip_bfloat16*)(ws + 92274688);   // [8][2048][128] bf16
    __hip_bfloat16* vbt  = (__hip_bfloat16*)(ws + 96468992);   // [8][128][2048] bf16 (V^T)
    __hip_bfloat16* ob   = (__hip_bfloat16*)(ws + 100663296);  // 2048x3072 bf16

    cast_all<<<30720, 256, 0, stream>>>(hs, wq, wk, wv, wo, hsb, wf, wob);

    gemm_tile<5, 1><<<512, 256, 73728, stream>>>(hsb, wf, qpre, kpre, vbt);

    norm_rope_fused<<<16384, 256, 0, stream>>>(qpre, kpre, qb, kb, qnw, knw, cosp, sinp);

    attn_kernel<<<256, 384, 79360, stream>>>(qb, kb, vbt, ob);

    gemm_tile<3, 0><<<512, 256, 57344, stream>>>(ob, wob, out, (void*)0, (void*)0);
}

// Round 12
// 203.645 us; speedup vs baseline: 1.0246x; 1.0246x over previous
//
#include <hip/hip_runtime.h>
#include <hip/hip_bf16.h>

#define S_LEN 2048
#define HIDV  3072
#define NHQ   24
#define NKVH  8
#define HDIM  128

typedef __bf16 bf16x8 __attribute__((ext_vector_type(8)));
typedef float  f32x4  __attribute__((ext_vector_type(4)));
typedef float  f32x16 __attribute__((ext_vector_type(16)));
typedef unsigned int u32;

__device__ __forceinline__ void gload_lds16(const void* g, void* l) {
    __builtin_amdgcn_global_load_lds((__attribute__((address_space(1))) void*)g,
                                     (__attribute__((address_space(3))) void*)l, 16, 0, 0);
}

// ---------------- fused cast f32 -> bf16 over 5 regions, 4 elems/thread ----------------
__global__ void cast_all(const float* __restrict__ hs, const float* __restrict__ wq,
                         const float* __restrict__ wk, const float* __restrict__ wv,
                         const float* __restrict__ wo,
                         __hip_bfloat16* __restrict__ hsb, __hip_bfloat16* __restrict__ wf,
                         __hip_bfloat16* __restrict__ wob) {
    int c = blockIdx.x * blockDim.x + threadIdx.x;   // chunk of 4 f32
    const float* src; __hip_bfloat16* dst; int off;
    if (c < 1572864)      { src = hs; dst = hsb;            off = c; }
    else if (c < 3932160) { src = wq; dst = wf;             off = c - 1572864; }
    else if (c < 4718592) { src = wk; dst = wf + 9437184;   off = c - 3932160; }
    else if (c < 5505024) { src = wv; dst = wf + 12582912;  off = c - 4718592; }
    else                  { src = wo; dst = wob;            off = c - 5505024; }
    float4 v = *(const float4*)(src + off * 4);
    union { __hip_bfloat16 h[4]; ushort4 u; } pk;
    pk.h[0] = __float2bfloat16(v.x);
    pk.h[1] = __float2bfloat16(v.y);
    pk.h[2] = __float2bfloat16(v.z);
    pk.h[3] = __float2bfloat16(v.w);
    *(ushort4*)(dst + off * 4) = pk.u;
}

// ============ 2-phase double-buffered GEMM, BM=128, BN=NF*32, BK=64, swizzled LDS ============
template<int NF, int MODE>
__global__ __launch_bounds__(256) void gemm_tile(const __hip_bfloat16* __restrict__ A,
                                                 const __hip_bfloat16* __restrict__ B,
                                                 void* __restrict__ C0, void* __restrict__ C1,
                                                 void* __restrict__ C2)
{
    extern __shared__ __align__(16) char smem[];
    const int tid = threadIdx.x;
    const int w    = tid >> 6;
    const int lane = tid & 63;
    const int lr = lane & 15, lg = lane >> 4;
    const int wr = w >> 1, wc = w & 1;

    const int wg = ((int)blockIdx.x & 7) * 64 + ((int)blockIdx.x >> 3);
    const int bn = wg >> 4, bm = wg & 15;

    f32x4 zf = {0.f, 0.f, 0.f, 0.f};
    f32x4 acc[4][NF];
#pragma unroll
    for (int i = 0; i < 4; ++i)
#pragma unroll
        for (int j = 0; j < NF; ++j) acc[i][j] = zf;

    const char* Ab = (const char*)A + (size_t)(bm * 128) * 6144;
    const char* Bb = (const char*)B + (size_t)(bn * NF * 32) * 6144;
    const int NT = 48;  // 3072 / 64

    int gaof[4], gbof[NF];
#pragma unroll
    for (int u_ = 0; u_ < 4; ++u_) {
        int u = tid + 256 * u_;
        int r_ = u >> 3, o_ = (u & 7) * 16;
        gaof[u_] = r_ * 6144 + (o_ ^ ((r_ & 7) << 4));
    }
#pragma unroll
    for (int u_ = 0; u_ < NF; ++u_) {
        int u = tid + 256 * u_;
        int r_ = u >> 3, o_ = (u & 7) * 16;
        gbof[u_] = r_ * 6144 + (o_ ^ ((r_ & 7) << 4));
    }

#define GT_STAGE(BUF, t) do {                                                       \
        const char* Abk_ = Ab + ((t) << 7);                                         \
        const char* Bbk_ = Bb + ((t) << 7);                                         \
        _Pragma("unroll")                                                           \
        for (int u_ = 0; u_ < 4; ++u_)                                              \
            gload_lds16(Abk_ + gaof[u_], smem + (BUF) * 16384 + tid * 16 + u_ * 4096); \
        _Pragma("unroll")                                                           \
        for (int u_ = 0; u_ < NF; ++u_)                                             \
            gload_lds16(Bbk_ + gbof[u_], smem + 32768 + (BUF) * (NF * 4096) + tid * 16 + u_ * 4096); \
    } while (0)

#define GT_COMPUTE(BUF) do {                                                        \
        bf16x8 af[4][2], bfr[NF][2];                                                \
        _Pragma("unroll")                                                           \
        for (int i = 0; i < 4; ++i) {                                               \
            int row = wr * 64 + i * 16 + lr;                                        \
            _Pragma("unroll")                                                       \
            for (int kk = 0; kk < 2; ++kk) {                                        \
                int cb = (kk * 64 + lg * 16) ^ ((row & 7) << 4);                    \
                af[i][kk] = *(const bf16x8*)(smem + (BUF) * 16384 + row * 128 + cb); \
            }                                                                       \
        }                                                                           \
        _Pragma("unroll")                                                           \
        for (int j = 0; j < NF; ++j) {                                              \
            int row = (wc * NF + j) * 16 + lr;                                      \
            _Pragma("unroll")                                                       \
            for (int kk = 0; kk < 2; ++kk) {                                        \
                int cb = (kk * 64 + lg * 16) ^ ((row & 7) << 4);                    \
                bfr[j][kk] = *(const bf16x8*)(smem + 32768 + (BUF) * (NF * 4096) + row * 128 + cb); \
            }                                                                       \
        }                                                                           \
        _Pragma("unroll")                                                           \
        for (int mi = 0; mi < 4; ++mi)                                              \
            _Pragma("unroll")                                                       \
            for (int ni = 0; ni < NF; ++ni)                                         \
                _Pragma("unroll")                                                   \
                for (int kk = 0; kk < 2; ++kk)                                      \
                    acc[mi][ni] = __builtin_amdgcn_mfma_f32_16x16x32_bf16(af[mi][kk], bfr[ni][kk], acc[mi][ni], 0, 0, 0); \
    } while (0)

    GT_STAGE(0, 0);
    __syncthreads();

    for (int t = 0; t < NT; t += 2) {
        GT_STAGE(1, t + 1);          // odd tile -> buf1
        GT_COMPUTE(0);               // even tile from buf0
        __syncthreads();
        if (t + 2 < NT) GT_STAGE(0, t + 2);
        GT_COMPUTE(1);
        __syncthreads();
    }
#undef GT_STAGE
#undef GT_COMPUTE

#pragma unroll
    for (int mi = 0; mi < 4; ++mi)
#pragma unroll
        for (int ni = 0; ni < NF; ++ni) {
            int row0 = bm * 128 + wr * 64 + mi * 16 + lg * 4;
            int col  = bn * NF * 32 + wc * NF * 16 + ni * 16 + lr;
            f32x4 v = acc[mi][ni];
            if (MODE == 0) {
#pragma unroll
                for (int j = 0; j < 4; ++j)
                    ((float*)C0)[(size_t)(row0 + j) * 3072 + col] = v[j];
            } else {
                if (col < 3072) {
#pragma unroll
                    for (int j = 0; j < 4; ++j)
                        ((__hip_bfloat16*)C0)[(size_t)(row0 + j) * 3072 + col] = __float2bfloat16(v[j]);
                } else if (col < 4096) {
#pragma unroll
                    for (int j = 0; j < 4; ++j)
                        ((__hip_bfloat16*)C1)[(size_t)(row0 + j) * 1024 + (col - 3072)] = __float2bfloat16(v[j]);
                } else {
                    union { __hip_bfloat16 h[4]; ushort4 u; } pk;
#pragma unroll
                    for (int j = 0; j < 4; ++j) pk.h[j] = __float2bfloat16(v[j]);
                    *(ushort4*)((__hip_bfloat16*)C2 + (size_t)(col - 4096) * 2048 + row0) = pk.u;
                }
            }
        }
}

// ---------------- fused RMSNorm + RoPE (q then k): one wave per row of 128 ----------------
__global__ void norm_rope_fused(const __hip_bfloat16* __restrict__ qpre,
                                const __hip_bfloat16* __restrict__ kpre,
                                __hip_bfloat16* __restrict__ qb, __hip_bfloat16* __restrict__ kb,
                                const float* __restrict__ qnw, const float* __restrict__ knw,
                                const float* __restrict__ cosp, const float* __restrict__ sinp)
{
    int gw = blockIdx.x * 4 + (threadIdx.x >> 6);
    int lane = threadIdx.x & 63;
    const __hip_bfloat16* row;
    const float* nw;
    __hip_bfloat16* outp;
    int s;
    if (gw < 49152) {  // Q: s = gw/24, h = gw%24
        s = gw / 24; int h = gw - s * 24;
        row  = qpre + (size_t)s * 3072 + h * HDIM;
        outp = qb   + (size_t)s * 3072 + h * HDIM;
        nw = qnw;
    } else {           // K: s = g/8, h = g%8; out kb[h][s][d]
        int g = gw - 49152;
        s = g >> 3; int h = g & 7;
        row  = kpre + (size_t)s * 1024 + h * HDIM;
        outp = kb + (size_t)h * 262144 + (size_t)s * 128;
        nw = knw;
    }
    float x1 = __bfloat162float(row[lane]), x2 = __bfloat162float(row[lane + 64]);
    float ss = x1 * x1 + x2 * x2;
#pragma unroll
    for (int xm = 1; xm < 64; xm <<= 1) ss += __shfl_xor(ss, xm, 64);
    float rs = rsqrtf(ss * (1.f / 128.f) + 1e-6f);
    float n1 = x1 * rs * (1.f + nw[lane]);
    float n2 = x2 * rs * (1.f + nw[lane + 64]);
    float c1 = cosp[s * HDIM + lane], c2 = cosp[s * HDIM + lane + 64];
    float s1 = sinp[s * HDIM + lane], s2 = sinp[s * HDIM + lane + 64];
    outp[lane]      = __float2bfloat16(n1 * c1 - n2 * s1);
    outp[lane + 64] = __float2bfloat16(n2 * c2 + n1 * s2);
}

// ---------------- Flash attention: 32x32 MFMA, in-register P, kv-split waves ----------------
// Grid 256 linear, XCD-pinned: kh = bid & 7, pb = bid >> 3. 384 thr / 6 waves =
// 3 heads x 2 kv-halves. Each wave: 32 q-rows (block half) x 32 kv of each 64-tile.
// Swapped QK^T: S^T = mfma(A=K, B=Q[regs]) -> lane holds q=lane&31 col, 16 kv rows.
// Softmax in-register (fixed max via softcap bound + tanh poly); P packed to bf16 and
// redistributed with 8 shfl_xor -> PV B-frags; O^T = mfma(A=V^T, B=P^T) partials per
// kv-half, merged pairwise through LDS once per q-block. LDS reads/tile/wave: 16 b128
// (vs 34 in the 16x16 version) -> attacks the measured LDS-throughput bound.
// LDS: K[2][64x256B] @0 (swz row&15), V[2][128x128B] @32768 (swz row&7);
// merge area reuses @0: 3 pairs x (16KB O + 128B l). Total 65536 B.
__global__ __launch_bounds__(384) void attn_kernel(
    const __hip_bfloat16* __restrict__ Q,
    const __hip_bfloat16* __restrict__ Kc,
    const __hip_bfloat16* __restrict__ Vt,
    __hip_bfloat16* __restrict__ O)
{
    extern __shared__ __align__(16) char smem[];
    const int bid = blockIdx.x;
    const int kh = bid & 7;      // XCD-pinned kv-head
    const int pb = bid >> 3;     // 0..31
    const int tid = threadIdx.x;
    const int w = tid >> 6;      // 0..5
    const int lane = tid & 63;
    const int ql = lane & 31, hi = lane >> 5;
    const int head = w >> 1;     // 0..2
    const int kvh = w & 1;       // kv-half
    const int h = kh * 3 + head;

    const char* kg = (const char*)(Kc + (size_t)kh * S_LEN * HDIM);
    const char* vg = (const char*)(Vt + (size_t)kh * HDIM * S_LEN);

    // hoisted staging offsets: K rows 256B swizzled by (row&15), V rows 128B by (row&7)
    int ksrc[4], vsrc[4];
#pragma unroll
    for (int i_ = 0; i_ < 4; ++i_) {
        int base_ = (tid + 256 * i_) * 16;
        int kr_ = base_ >> 8, kc_ = base_ & 255;
        ksrc[i_] = kr_ * 256 + (kc_ ^ ((kr_ & 15) << 4));
        int vr_ = base_ >> 7, vc_ = base_ & 127;
        vsrc[i_] = vr_ * 4096 + (vc_ ^ ((vr_ & 7) << 4));
    }

#define ATT_STAGE(b, j0s) do {                                                      \
        if (tid < 256) {                                                            \
            const char* kgs_ = kg + (size_t)(j0s) * 256;                            \
            const char* vgs_ = vg + (size_t)(j0s) * 2;                              \
            _Pragma("unroll")                                                       \
            for (int i_ = 0; i_ < 4; ++i_) {                                        \
                gload_lds16(kgs_ + ksrc[i_], smem + (b) * 16384 + tid * 16 + i_ * 4096); \
                gload_lds16(vgs_ + vsrc[i_], smem + 32768 + (b) * 16384 + tid * 16 + i_ * 4096); \
            } } } while (0)

    for (int half = 0; half < 2; ++half) {
        const int hb = half ? (63 - pb) : pb;
        const int q0 = hb * 32;
        const int qg = q0 + ql;
        const int jtmax = (q0 + 31) >> 6;

        // Q fragments (B-operand): lane holds Q[q0+ql][d = step*16 + hi*8 + 0..7]
        bf16x8 qf[8];
        {
            const char* qp = (const char*)Q + (size_t)(q0 + ql) * 6144 + h * 256 + hi * 16;
#pragma unroll
            for (int st = 0; st < 8; ++st) qf[st] = *(const bf16x8*)(qp + st * 32);
        }

        f32x16 acc_o[4] = {};
        float lacc = 0.f;

        ATT_STAGE(0, 0);
        __syncthreads();

        int buf = 0;
        for (int jt = 0; jt <= jtmax; ++jt) {
            if (jt < jtmax) ATT_STAGE(buf ^ 1, (jt + 1) * 64);

            const char* Kb = smem + buf * 16384;
            const char* Vb = smem + 32768 + buf * 16384;

            // S^T[kv][q] = K x Q^T over d=128 (8 k-steps of 16)
            f32x16 sacc = {};
            const int krow = kvh * 32 + ql;
            const int kswz = (krow & 15) << 4;
#pragma unroll
            for (int st = 0; st < 8; ++st) {
                bf16x8 kf = *(const bf16x8*)(Kb + krow * 256 + ((st * 32 + hi * 16) ^ kswz));
                sacc = __builtin_amdgcn_mfma_f32_32x32x16_bf16(kf, qf[st], sacc, 0, 0, 0);
            }

            // softmax (fixed max): p = exp(50*tanh(s*scl/50) - 30); causal mask on diag tile
            const bool diag = (jt == jtmax);
            const int kvb = jt * 64 + kvh * 32 + 4 * hi;
            float p[16];
#pragma unroll
            for (int reg = 0; reg < 16; ++reg) {
                float sv = sacc[reg];
                float x2   = sv * sv * 3.125e-06f;
                float poly = fmaf(x2, fmaf(x2, 0.13333333f, -0.33333333f), 1.0f);
                float t    = sv * 0.08838834764831845f * poly;
                float pp   = __expf(t - 30.f);
                int kvgl = kvb + (reg & 3) + 8 * (reg >> 2);
                if (diag && kvgl > qg) pp = 0.f;
                lacc += pp;
                p[reg] = pp;
            }

            // pack to bf16 pairs: wpk[o][pp] holds kv = 8o + 4hi + {2pp, 2pp+1}
            u32 wpk[4][2];
#pragma unroll
            for (int o = 0; o < 4; ++o)
#pragma unroll
                for (int px = 0; px < 2; ++px) {
                    union { __hip_bfloat16 hh[2]; u32 u; } cv;
                    cv.hh[0] = __float2bfloat16(p[4 * o + 2 * px]);
                    cv.hh[1] = __float2bfloat16(p[4 * o + 2 * px + 1]);
                    wpk[o][px] = cv.u;
                }

            // redistribute -> PV B-frags: slice s needs kv = s*16 + hi*8 + j
            bf16x8 pfrag[2];
#pragma unroll
            for (int s = 0; s < 2; ++s) {
                union { u32 u[4]; bf16x8 v; } cv;
#pragma unroll
                for (int px = 0; px < 2; ++px) {
                    u32 a = wpk[2 * s][px], b = wpk[2 * s + 1][px];
                    u32 bp = (u32)__shfl_xor((int)b, 32, 64);
                    u32 ap = (u32)__shfl_xor((int)a, 32, 64);
                    cv.u[px]     = hi ? bp : a;
                    cv.u[2 + px] = hi ? b  : ap;
                }
                pfrag[s] = cv.v;
            }

            // O^T[d][q] += V^T x P  (4 d-tiles x 2 kv-slices)
#pragma unroll
            for (int dt = 0; dt < 4; ++dt) {
                const int vrow = dt * 32 + ql;
                const int vswz = (vrow & 7) << 4;
#pragma unroll
                for (int s = 0; s < 2; ++s) {
                    bf16x8 vf = *(const bf16x8*)(Vb + vrow * 128 +
                                    ((kvh * 64 + s * 32 + hi * 16) ^ vswz));
                    acc_o[dt] = __builtin_amdgcn_mfma_f32_32x32x16_bf16(vf, pfrag[s], acc_o[dt], 0, 0, 0);
                }
            }
            __syncthreads();
            buf ^= 1;
        }

        // -------- pairwise merge (kv-half 0 + 1) through LDS, then store --------
        float lacc2 = lacc + __shfl_xor(lacc, 32, 64);
        const int pairbase = head * 16512;

        if (kvh == 0) {
#pragma unroll
            for (int dt = 0; dt < 4; ++dt)
#pragma unroll
                for (int reg = 0; reg < 16; ++reg) {
                    int d = dt * 32 + (reg & 3) + 8 * (reg >> 2) + 4 * hi;
                    *(float*)(smem + pairbase + ql * 512 + ((d * 4) ^ ((ql & 15) << 5))) = acc_o[dt][reg];
                }
            *(float*)(smem + pairbase + 16384 + ql * 4) = lacc2;
        }
        __syncthreads();
        if (kvh == 1) {
            float ltot = lacc2 + *(const float*)(smem + pairbase + 16384 + ql * 4);
            float inv = __builtin_amdgcn_rcpf(ltot);
#pragma unroll
            for (int dt = 0; dt < 4; ++dt)
#pragma unroll
                for (int reg = 0; reg < 16; ++reg) {
                    int d = dt * 32 + (reg & 3) + 8 * (reg >> 2) + 4 * hi;
                    float m = acc_o[dt][reg] +
                        *(const float*)(smem + pairbase + ql * 512 + ((d * 4) ^ ((ql & 15) << 5)));
                    acc_o[dt][reg] = m * inv;
                }
            __hip_bfloat16* orow = O + (size_t)(q0 + ql) * HIDV + h * HDIM;
#pragma unroll
            for (int dt = 0; dt < 4; ++dt)
#pragma unroll
                for (int rq = 0; rq < 4; ++rq) {
                    int d0 = dt * 32 + 8 * rq + 4 * hi;
                    union { __hip_bfloat16 hh[4]; ushort4 u; } pk;
#pragma unroll
                    for (int j = 0; j < 4; ++j) pk.hh[j] = __float2bfloat16(acc_o[dt][4 * rq + j]);
                    *(ushort4*)(orow + d0) = pk.u;
                }
        }
        __syncthreads();   // merge area reads done before next half restages K/V
    }
#undef ATT_STAGE
}

extern "C" void kernel_launch(void* const* d_in, const int* in_sizes, int n_in,
                              void* d_out, int out_size, void* d_ws, size_t ws_size,
                              hipStream_t stream) {
    const float* hs   = (const float*)d_in[0];
    const float* cosp = (const float*)d_in[1];
    const float* sinp = (const float*)d_in[2];
    // d_in[3] attention_mask — exactly causal, applied analytically in attn_kernel
    const float* wq  = (const float*)d_in[4];
    const float* wk  = (const float*)d_in[5];
    const float* wv  = (const float*)d_in[6];
    const float* wo  = (const float*)d_in[7];
    const float* qnw = (const float*)d_in[8];
    const float* knw = (const float*)d_in[9];
    float* out = (float*)d_out;

    char* ws = (char*)d_ws;
    __hip_bfloat16* hsb  = (__hip_bfloat16*)(ws + 0);          // 2048x3072 bf16
    __hip_bfloat16* wf   = (__hip_bfloat16*)(ws + 12582912);   // 5120x3072 bf16 fused QKV weight
    __hip_bfloat16* wob  = (__hip_bfloat16*)(ws + 44040192);   // 3072x3072 bf16
    __hip_bfloat16* qpre = (__hip_bfloat16*)(ws + 62914560);   // 2048x3072 bf16 (pre-norm Q)
    __hip_bfloat16* kpre = (__hip_bfloat16*)(ws + 75497472);   // 2048x1024 bf16 (pre-norm K)
    __hip_bfloat16* qb   = (__hip_bfloat16*)(ws + 79691776);   // 2048x3072 bf16
    __hip_bfloat16* kb   = (__hip_bfloat16*)(ws + 92274688);   // [8][2048][128] bf16
    __hip_bfloat16* vbt  = (__hip_bfloat16*)(ws + 96468992);   // [8][128][2048] bf16 (V^T)
    __hip_bfloat16* ob   = (__hip_bfloat16*)(ws + 100663296);  // 2048x3072 bf16

    cast_all<<<30720, 256, 0, stream>>>(hs, wq, wk, wv, wo, hsb, wf, wob);

    gemm_tile<5, 1><<<512, 256, 73728, stream>>>(hsb, wf, qpre, kpre, vbt);

    norm_rope_fused<<<16384, 256, 0, stream>>>(qpre, kpre, qb, kb, qnw, knw, cosp, sinp);

    attn_kernel<<<256, 384, 65536, stream>>>(qb, kb, vbt, ob);

    gemm_tile<3, 0><<<512, 256, 57344, stream>>>(ob, wob, out, (void*)0, (void*)0);
}

// Round 13
// 198.189 us; speedup vs baseline: 1.0528x; 1.0275x over previous
//
#include <hip/hip_runtime.h>
#include <hip/hip_bf16.h>

#define S_LEN 2048
#define HIDV  3072
#define NHQ   24
#define NKVH  8
#define HDIM  128

typedef __bf16 bf16x8 __attribute__((ext_vector_type(8)));
typedef float  f32x4  __attribute__((ext_vector_type(4)));
typedef float  f32x16 __attribute__((ext_vector_type(16)));
typedef unsigned int u32;

__device__ __forceinline__ void gload_lds16(const void* g, void* l) {
    __builtin_amdgcn_global_load_lds((__attribute__((address_space(1))) void*)g,
                                     (__attribute__((address_space(3))) void*)l, 16, 0, 0);
}

// ---------------- fused cast f32 -> bf16 over 5 regions, 4 elems/thread ----------------
__global__ void cast_all(const float* __restrict__ hs, const float* __restrict__ wq,
                         const float* __restrict__ wk, const float* __restrict__ wv,
                         const float* __restrict__ wo,
                         __hip_bfloat16* __restrict__ hsb, __hip_bfloat16* __restrict__ wf,
                         __hip_bfloat16* __restrict__ wob) {
    int c = blockIdx.x * blockDim.x + threadIdx.x;   // chunk of 4 f32
    const float* src; __hip_bfloat16* dst; int off;
    if (c < 1572864)      { src = hs; dst = hsb;            off = c; }
    else if (c < 3932160) { src = wq; dst = wf;             off = c - 1572864; }
    else if (c < 4718592) { src = wk; dst = wf + 9437184;   off = c - 3932160; }
    else if (c < 5505024) { src = wv; dst = wf + 12582912;  off = c - 4718592; }
    else                  { src = wo; dst = wob;            off = c - 5505024; }
    float4 v = *(const float4*)(src + off * 4);
    union { __hip_bfloat16 h[4]; ushort4 u; } pk;
    pk.h[0] = __float2bfloat16(v.x);
    pk.h[1] = __float2bfloat16(v.y);
    pk.h[2] = __float2bfloat16(v.z);
    pk.h[3] = __float2bfloat16(v.w);
    *(ushort4*)(dst + off * 4) = pk.u;
}

// ============ 2-phase double-buffered GEMM, BM=128, BN=NF*32, BK=64, swizzled LDS ============
template<int NF, int MODE>
__global__ __launch_bounds__(256) void gemm_tile(const __hip_bfloat16* __restrict__ A,
                                                 const __hip_bfloat16* __restrict__ B,
                                                 void* __restrict__ C0, void* __restrict__ C1,
                                                 void* __restrict__ C2)
{
    extern __shared__ __align__(16) char smem[];
    const int tid = threadIdx.x;
    const int w    = tid >> 6;
    const int lane = tid & 63;
    const int lr = lane & 15, lg = lane >> 4;
    const int wr = w >> 1, wc = w & 1;

    const int wg = ((int)blockIdx.x & 7) * 64 + ((int)blockIdx.x >> 3);
    const int bn = wg >> 4, bm = wg & 15;

    f32x4 zf = {0.f, 0.f, 0.f, 0.f};
    f32x4 acc[4][NF];
#pragma unroll
    for (int i = 0; i < 4; ++i)
#pragma unroll
        for (int j = 0; j < NF; ++j) acc[i][j] = zf;

    const char* Ab = (const char*)A + (size_t)(bm * 128) * 6144;
    const char* Bb = (const char*)B + (size_t)(bn * NF * 32) * 6144;
    const int NT = 48;  // 3072 / 64

    int gaof[4], gbof[NF];
#pragma unroll
    for (int u_ = 0; u_ < 4; ++u_) {
        int u = tid + 256 * u_;
        int r_ = u >> 3, o_ = (u & 7) * 16;
        gaof[u_] = r_ * 6144 + (o_ ^ ((r_ & 7) << 4));
    }
#pragma unroll
    for (int u_ = 0; u_ < NF; ++u_) {
        int u = tid + 256 * u_;
        int r_ = u >> 3, o_ = (u & 7) * 16;
        gbof[u_] = r_ * 6144 + (o_ ^ ((r_ & 7) << 4));
    }

#define GT_STAGE(BUF, t) do {                                                       \
        const char* Abk_ = Ab + ((t) << 7);                                         \
        const char* Bbk_ = Bb + ((t) << 7);                                         \
        _Pragma("unroll")                                                           \
        for (int u_ = 0; u_ < 4; ++u_)                                              \
            gload_lds16(Abk_ + gaof[u_], smem + (BUF) * 16384 + tid * 16 + u_ * 4096); \
        _Pragma("unroll")                                                           \
        for (int u_ = 0; u_ < NF; ++u_)                                             \
            gload_lds16(Bbk_ + gbof[u_], smem + 32768 + (BUF) * (NF * 4096) + tid * 16 + u_ * 4096); \
    } while (0)

#define GT_COMPUTE(BUF) do {                                                        \
        bf16x8 af[4][2], bfr[NF][2];                                                \
        _Pragma("unroll")                                                           \
        for (int i = 0; i < 4; ++i) {                                               \
            int row = wr * 64 + i * 16 + lr;                                        \
            _Pragma("unroll")                                                       \
            for (int kk = 0; kk < 2; ++kk) {                                        \
                int cb = (kk * 64 + lg * 16) ^ ((row & 7) << 4);                    \
                af[i][kk] = *(const bf16x8*)(smem + (BUF) * 16384 + row * 128 + cb); \
            }                                                                       \
        }                                                                           \
        _Pragma("unroll")                                                           \
        for (int j = 0; j < NF; ++j) {                                              \
            int row = (wc * NF + j) * 16 + lr;                                      \
            _Pragma("unroll")                                                       \
            for (int kk = 0; kk < 2; ++kk) {                                        \
                int cb = (kk * 64 + lg * 16) ^ ((row & 7) << 4);                    \
                bfr[j][kk] = *(const bf16x8*)(smem + 32768 + (BUF) * (NF * 4096) + row * 128 + cb); \
            }                                                                       \
        }                                                                           \
        _Pragma("unroll")                                                           \
        for (int mi = 0; mi < 4; ++mi)                                              \
            _Pragma("unroll")                                                       \
            for (int ni = 0; ni < NF; ++ni)                                         \
                _Pragma("unroll")                                                   \
                for (int kk = 0; kk < 2; ++kk)                                      \
                    acc[mi][ni] = __builtin_amdgcn_mfma_f32_16x16x32_bf16(af[mi][kk], bfr[ni][kk], acc[mi][ni], 0, 0, 0); \
    } while (0)

    GT_STAGE(0, 0);
    __syncthreads();

    for (int t = 0; t < NT; t += 2) {
        GT_STAGE(1, t + 1);          // odd tile -> buf1
        GT_COMPUTE(0);               // even tile from buf0
        __syncthreads();
        if (t + 2 < NT) GT_STAGE(0, t + 2);
        GT_COMPUTE(1);
        __syncthreads();
    }
#undef GT_STAGE
#undef GT_COMPUTE

#pragma unroll
    for (int mi = 0; mi < 4; ++mi)
#pragma unroll
        for (int ni = 0; ni < NF; ++ni) {
            int row0 = bm * 128 + wr * 64 + mi * 16 + lg * 4;
            int col  = bn * NF * 32 + wc * NF * 16 + ni * 16 + lr;
            f32x4 v = acc[mi][ni];
            if (MODE == 0) {
#pragma unroll
                for (int j = 0; j < 4; ++j)
                    ((float*)C0)[(size_t)(row0 + j) * 3072 + col] = v[j];
            } else {
                if (col < 3072) {
#pragma unroll
                    for (int j = 0; j < 4; ++j)
                        ((__hip_bfloat16*)C0)[(size_t)(row0 + j) * 3072 + col] = __float2bfloat16(v[j]);
                } else if (col < 4096) {
#pragma unroll
                    for (int j = 0; j < 4; ++j)
                        ((__hip_bfloat16*)C1)[(size_t)(row0 + j) * 1024 + (col - 3072)] = __float2bfloat16(v[j]);
                } else {
                    union { __hip_bfloat16 h[4]; ushort4 u; } pk;
#pragma unroll
                    for (int j = 0; j < 4; ++j) pk.h[j] = __float2bfloat16(v[j]);
                    *(ushort4*)((__hip_bfloat16*)C2 + (size_t)(col - 4096) * 2048 + row0) = pk.u;
                }
            }
        }
}

// ---------------- fused RMSNorm + RoPE (q then k): one wave per row of 128 ----------------
__global__ void norm_rope_fused(const __hip_bfloat16* __restrict__ qpre,
                                const __hip_bfloat16* __restrict__ kpre,
                                __hip_bfloat16* __restrict__ qb, __hip_bfloat16* __restrict__ kb,
                                const float* __restrict__ qnw, const float* __restrict__ knw,
                                const float* __restrict__ cosp, const float* __restrict__ sinp)
{
    int gw = blockIdx.x * 4 + (threadIdx.x >> 6);
    int lane = threadIdx.x & 63;
    const __hip_bfloat16* row;
    const float* nw;
    __hip_bfloat16* outp;
    int s;
    if (gw < 49152) {  // Q: s = gw/24, h = gw%24
        s = gw / 24; int h = gw - s * 24;
        row  = qpre + (size_t)s * 3072 + h * HDIM;
        outp = qb   + (size_t)s * 3072 + h * HDIM;
        nw = qnw;
    } else {           // K: s = g/8, h = g%8; out kb[h][s][d]
        int g = gw - 49152;
        s = g >> 3; int h = g & 7;
        row  = kpre + (size_t)s * 1024 + h * HDIM;
        outp = kb + (size_t)h * 262144 + (size_t)s * 128;
        nw = knw;
    }
    float x1 = __bfloat162float(row[lane]), x2 = __bfloat162float(row[lane + 64]);
    float ss = x1 * x1 + x2 * x2;
#pragma unroll
    for (int xm = 1; xm < 64; xm <<= 1) ss += __shfl_xor(ss, xm, 64);
    float rs = rsqrtf(ss * (1.f / 128.f) + 1e-6f);
    float n1 = x1 * rs * (1.f + nw[lane]);
    float n2 = x2 * rs * (1.f + nw[lane + 64]);
    float c1 = cosp[s * HDIM + lane], c2 = cosp[s * HDIM + lane + 64];
    float s1 = sinp[s * HDIM + lane], s2 = sinp[s * HDIM + lane + 64];
    outp[lane]      = __float2bfloat16(n1 * c1 - n2 * s1);
    outp[lane + 64] = __float2bfloat16(n2 * c2 + n1 * s2);
}

// ---------------- Flash attention: 32x32 MFMA, in-register P, 2 blocks/CU ----------------
// Grid 512 linear: half = bid>>8, kh = bid&7, pb = (bid&255)>>3, q-block = half?63-pb:pb.
// Round-robin dispatch puts bid and bid+256 on the same CU -> per-CU work is exactly
// 33 tiles for every pb, both halves share the kv-head (same XCD L2 pin), and the CU
// runs 12 waves (30% occ) instead of 6 -> latency chains overlap (this was the r12 bound).
// Per wave: 32 q-rows x 32 kv of each 64-tile (3 heads x 2 kv-halves = 6 waves).
// Swapped QK^T (S^T = K x Q), in-register softmax, shfl-redistributed P, O^T = V^T x P,
// pairwise merge via LDS. LDS 64 KiB (2 blocks x 64 = 128 <= 160 KiB/CU).
__global__ __launch_bounds__(384) void attn_kernel(
    const __hip_bfloat16* __restrict__ Q,
    const __hip_bfloat16* __restrict__ Kc,
    const __hip_bfloat16* __restrict__ Vt,
    __hip_bfloat16* __restrict__ O)
{
    extern __shared__ __align__(16) char smem[];
    const int bid = blockIdx.x;
    const int half = bid >> 8;
    const int b2 = bid & 255;
    const int kh = b2 & 7;       // XCD-pinned kv-head
    const int pb = b2 >> 3;      // 0..31
    const int hb = half ? (63 - pb) : pb;
    const int tid = threadIdx.x;
    const int w = tid >> 6;      // 0..5
    const int lane = tid & 63;
    const int ql = lane & 31, hi = lane >> 5;
    const int head = w >> 1;     // 0..2
    const int kvh = w & 1;       // kv-half
    const int h = kh * 3 + head;

    const char* kg = (const char*)(Kc + (size_t)kh * S_LEN * HDIM);
    const char* vg = (const char*)(Vt + (size_t)kh * HDIM * S_LEN);

    // hoisted staging offsets: K rows 256B swizzled by (row&15), V rows 128B by (row&7)
    int ksrc[4], vsrc[4];
#pragma unroll
    for (int i_ = 0; i_ < 4; ++i_) {
        int base_ = (tid + 256 * i_) * 16;
        int kr_ = base_ >> 8, kc_ = base_ & 255;
        ksrc[i_] = kr_ * 256 + (kc_ ^ ((kr_ & 15) << 4));
        int vr_ = base_ >> 7, vc_ = base_ & 127;
        vsrc[i_] = vr_ * 4096 + (vc_ ^ ((vr_ & 7) << 4));
    }

#define ATT_STAGE(b, j0s) do {                                                      \
        if (tid < 256) {                                                            \
            const char* kgs_ = kg + (size_t)(j0s) * 256;                            \
            const char* vgs_ = vg + (size_t)(j0s) * 2;                              \
            _Pragma("unroll")                                                       \
            for (int i_ = 0; i_ < 4; ++i_) {                                        \
                gload_lds16(kgs_ + ksrc[i_], smem + (b) * 16384 + tid * 16 + i_ * 4096); \
                gload_lds16(vgs_ + vsrc[i_], smem + 32768 + (b) * 16384 + tid * 16 + i_ * 4096); \
            } } } while (0)

    {
        const int q0 = hb * 32;
        const int qg = q0 + ql;
        const int jtmax = (q0 + 31) >> 6;

        // Q fragments (B-operand): lane holds Q[q0+ql][d = step*16 + hi*8 + 0..7]
        bf16x8 qf[8];
        {
            const char* qp = (const char*)Q + (size_t)(q0 + ql) * 6144 + h * 256 + hi * 16;
#pragma unroll
            for (int st = 0; st < 8; ++st) qf[st] = *(const bf16x8*)(qp + st * 32);
        }

        f32x16 acc_o[4] = {};
        float lacc = 0.f;

        ATT_STAGE(0, 0);
        __syncthreads();

        int buf = 0;
        for (int jt = 0; jt <= jtmax; ++jt) {
            if (jt < jtmax) ATT_STAGE(buf ^ 1, (jt + 1) * 64);

            const char* Kb = smem + buf * 16384;
            const char* Vb = smem + 32768 + buf * 16384;

            // S^T[kv][q] = K x Q^T over d=128 (8 k-steps of 16)
            f32x16 sacc = {};
            const int krow = kvh * 32 + ql;
            const int kswz = (krow & 15) << 4;
#pragma unroll
            for (int st = 0; st < 8; ++st) {
                bf16x8 kf = *(const bf16x8*)(Kb + krow * 256 + ((st * 32 + hi * 16) ^ kswz));
                sacc = __builtin_amdgcn_mfma_f32_32x32x16_bf16(kf, qf[st], sacc, 0, 0, 0);
            }

            // softmax (fixed max): p = exp(50*tanh(s*scl/50) - 30); causal mask on diag tile
            const bool diag = (jt == jtmax);
            const int kvb = jt * 64 + kvh * 32 + 4 * hi;
            float p[16];
#pragma unroll
            for (int reg = 0; reg < 16; ++reg) {
                float sv = sacc[reg];
                float x2   = sv * sv * 3.125e-06f;
                float poly = fmaf(x2, fmaf(x2, 0.13333333f, -0.33333333f), 1.0f);
                float t    = sv * 0.08838834764831845f * poly;
                float pp   = __expf(t - 30.f);
                int kvgl = kvb + (reg & 3) + 8 * (reg >> 2);
                if (diag && kvgl > qg) pp = 0.f;
                lacc += pp;
                p[reg] = pp;
            }

            // pack to bf16 pairs: wpk[o][pp] holds kv = 8o + 4hi + {2pp, 2pp+1}
            u32 wpk[4][2];
#pragma unroll
            for (int o = 0; o < 4; ++o)
#pragma unroll
                for (int px = 0; px < 2; ++px) {
                    union { __hip_bfloat16 hh[2]; u32 u; } cv;
                    cv.hh[0] = __float2bfloat16(p[4 * o + 2 * px]);
                    cv.hh[1] = __float2bfloat16(p[4 * o + 2 * px + 1]);
                    wpk[o][px] = cv.u;
                }

            // redistribute -> PV B-frags: slice s needs kv = s*16 + hi*8 + j
            bf16x8 pfrag[2];
#pragma unroll
            for (int s = 0; s < 2; ++s) {
                union { u32 u[4]; bf16x8 v; } cv;
#pragma unroll
                for (int px = 0; px < 2; ++px) {
                    u32 a = wpk[2 * s][px], b = wpk[2 * s + 1][px];
                    u32 bp = (u32)__shfl_xor((int)b, 32, 64);
                    u32 ap = (u32)__shfl_xor((int)a, 32, 64);
                    cv.u[px]     = hi ? bp : a;
                    cv.u[2 + px] = hi ? b  : ap;
                }
                pfrag[s] = cv.v;
            }

            // O^T[d][q] += V^T x P  (4 d-tiles x 2 kv-slices)
#pragma unroll
            for (int dt = 0; dt < 4; ++dt) {
                const int vrow = dt * 32 + ql;
                const int vswz = (vrow & 7) << 4;
#pragma unroll
                for (int s = 0; s < 2; ++s) {
                    bf16x8 vf = *(const bf16x8*)(Vb + vrow * 128 +
                                    ((kvh * 64 + s * 32 + hi * 16) ^ vswz));
                    acc_o[dt] = __builtin_amdgcn_mfma_f32_32x32x16_bf16(vf, pfrag[s], acc_o[dt], 0, 0, 0);
                }
            }
            __syncthreads();
            buf ^= 1;
        }

        // -------- pairwise merge (kv-half 0 + 1) through LDS, then store --------
        float lacc2 = lacc + __shfl_xor(lacc, 32, 64);
        const int pairbase = head * 16512;

        if (kvh == 0) {
#pragma unroll
            for (int dt = 0; dt < 4; ++dt)
#pragma unroll
                for (int reg = 0; reg < 16; ++reg) {
                    int d = dt * 32 + (reg & 3) + 8 * (reg >> 2) + 4 * hi;
                    *(float*)(smem + pairbase + ql * 512 + ((d * 4) ^ ((ql & 15) << 5))) = acc_o[dt][reg];
                }
            *(float*)(smem + pairbase + 16384 + ql * 4) = lacc2;
        }
        __syncthreads();
        if (kvh == 1) {
            float ltot = lacc2 + *(const float*)(smem + pairbase + 16384 + ql * 4);
            float inv = __builtin_amdgcn_rcpf(ltot);
#pragma unroll
            for (int dt = 0; dt < 4; ++dt)
#pragma unroll
                for (int reg = 0; reg < 16; ++reg) {
                    int d = dt * 32 + (reg & 3) + 8 * (reg >> 2) + 4 * hi;
                    float m = acc_o[dt][reg] +
                        *(const float*)(smem + pairbase + ql * 512 + ((d * 4) ^ ((ql & 15) << 5)));
                    acc_o[dt][reg] = m * inv;
                }
            __hip_bfloat16* orow = O + (size_t)(q0 + ql) * HIDV + h * HDIM;
#pragma unroll
            for (int dt = 0; dt < 4; ++dt)
#pragma unroll
                for (int rq = 0; rq < 4; ++rq) {
                    int d0 = dt * 32 + 8 * rq + 4 * hi;
                    union { __hip_bfloat16 hh[4]; ushort4 u; } pk;
#pragma unroll
                    for (int j = 0; j < 4; ++j) pk.hh[j] = __float2bfloat16(acc_o[dt][4 * rq + j]);
                    *(ushort4*)(orow + d0) = pk.u;
                }
        }
    }
#undef ATT_STAGE
}

extern "C" void kernel_launch(void* const* d_in, const int* in_sizes, int n_in,
                              void* d_out, int out_size, void* d_ws, size_t ws_size,
                              hipStream_t stream) {
    const float* hs   = (const float*)d_in[0];
    const float* cosp = (const float*)d_in[1];
    const float* sinp = (const float*)d_in[2];
    // d_in[3] attention_mask — exactly causal, applied analytically in attn_kernel
    const float* wq  = (const float*)d_in[4];
    const float* wk  = (const float*)d_in[5];
    const float* wv  = (const float*)d_in[6];
    const float* wo  = (const float*)d_in[7];
    const float* qnw = (const float*)d_in[8];
    const float* knw = (const float*)d_in[9];
    float* out = (float*)d_out;

    char* ws = (char*)d_ws;
    __hip_bfloat16* hsb  = (__hip_bfloat16*)(ws + 0);          // 2048x3072 bf16
    __hip_bfloat16* wf   = (__hip_bfloat16*)(ws + 12582912);   // 5120x3072 bf16 fused QKV weight
    __hip_bfloat16* wob  = (__hip_bfloat16*)(ws + 44040192);   // 3072x3072 bf16
    __hip_bfloat16* qpre = (__hip_bfloat16*)(ws + 62914560);   // 2048x3072 bf16 (pre-norm Q)
    __hip_bfloat16* kpre = (__hip_bfloat16*)(ws + 75497472);   // 2048x1024 bf16 (pre-norm K)
    __hip_bfloat16* qb   = (__hip_bfloat16*)(ws + 79691776);   // 2048x3072 bf16
    __hip_bfloat16* kb   = (__hip_bfloat16*)(ws + 92274688);   // [8][2048][128] bf16
    __hip_bfloat16* vbt  = (__hip_bfloat16*)(ws + 96468992);   // [8][128][2048] bf16 (V^T)
    __hip_bfloat16* ob   = (__hip_bfloat16*)(ws + 100663296);  // 2048x3072 bf16

    cast_all<<<30720, 256, 0, stream>>>(hs, wq, wk, wv, wo, hsb, wf, wob);

    gemm_tile<5, 1><<<512, 256, 73728, stream>>>(hsb, wf, qpre, kpre, vbt);

    norm_rope_fused<<<16384, 256, 0, stream>>>(qpre, kpre, qb, kb, qnw, knw, cosp, sinp);

    attn_kernel<<<512, 384, 65536, stream>>>(qb, kb, vbt, ob);

    gemm_tile<3, 0><<<512, 256, 57344, stream>>>(ob, wob, out, (void*)0, (void*)0);
}